// Round 1
// baseline (1860.726 us; speedup 1.0000x reference)
//
#include <hip/hip_runtime.h>
#include <math.h>

#define BSZ 4
#define SEQ 2048
#define INDIM 32
#define DM 256
#define ED 512
#define NST 16
#define DTR 16
#define MROWS (BSZ * SEQ) /* 8192 */

__device__ __forceinline__ float silu_f(float x) { return x / (1.f + __expf(-x)); }

// ---------------- generic NT GEMM: C[m,n] = sum_k A[m,k(lda)] * B[n,k]  ----------------
// BM=BN=64, BK=16, 256 threads, 4x4 per thread. M must be a multiple of 64; N,K guarded.
template <bool BIAS, bool ACCUM>
__global__ __launch_bounds__(256) void gemm_nt(const float* __restrict__ A,
                                               const float* __restrict__ B,
                                               const float* __restrict__ bias,
                                               float* __restrict__ C,
                                               int M, int N, int K, int lda) {
  __shared__ float As[16][65];
  __shared__ float Bs[16][65];
  const int tid = threadIdx.x;
  const int m0 = blockIdx.y * 64;
  const int n0 = blockIdx.x * 64;
  const int tm = tid & 15, tn = tid >> 4;
  const int lrow = tid >> 2;
  const int lk = (tid & 3) << 2;
  float acc[4][4] = {};
  for (int k0 = 0; k0 < K; k0 += 16) {
    {
      const float4 a = *(const float4*)(A + (size_t)(m0 + lrow) * lda + k0 + lk);
      As[lk + 0][lrow] = a.x; As[lk + 1][lrow] = a.y;
      As[lk + 2][lrow] = a.z; As[lk + 3][lrow] = a.w;
    }
    {
      float4 b = make_float4(0.f, 0.f, 0.f, 0.f);
      if (n0 + lrow < N) b = *(const float4*)(B + (size_t)(n0 + lrow) * K + k0 + lk);
      Bs[lk + 0][lrow] = b.x; Bs[lk + 1][lrow] = b.y;
      Bs[lk + 2][lrow] = b.z; Bs[lk + 3][lrow] = b.w;
    }
    __syncthreads();
#pragma unroll
    for (int k = 0; k < 16; k++) {
      float a4[4], b4[4];
#pragma unroll
      for (int i = 0; i < 4; i++) a4[i] = As[k][tm * 4 + i];
#pragma unroll
      for (int j = 0; j < 4; j++) b4[j] = Bs[k][tn * 4 + j];
#pragma unroll
      for (int i = 0; i < 4; i++)
#pragma unroll
        for (int j = 0; j < 4; j++) acc[i][j] = fmaf(a4[i], b4[j], acc[i][j]);
    }
    __syncthreads();
  }
#pragma unroll
  for (int i = 0; i < 4; i++) {
    const int m = m0 + tm * 4 + i;
#pragma unroll
    for (int j = 0; j < 4; j++) {
      const int n = n0 + tn * 4 + j;
      if (n < N) {
        float v = acc[i][j];
        if (BIAS) v += bias[n];
        float* p = C + (size_t)m * N + n;
        if (ACCUM) v += *p;
        *p = v;
      }
    }
  }
}

// ---------------- rmsnorm over DM=256 ----------------
__global__ __launch_bounds__(256) void rmsnorm_k(const float* __restrict__ h,
                                                 const float* __restrict__ w,
                                                 float* __restrict__ out) {
  __shared__ float sh[4];
  __shared__ float sscale;
  const int row = blockIdx.x;
  const int tid = threadIdx.x;
  const float v = h[(size_t)row * DM + tid];
  float s = v * v;
#pragma unroll
  for (int off = 32; off; off >>= 1) s += __shfl_xor(s, off, 64);
  if ((tid & 63) == 0) sh[tid >> 6] = s;
  __syncthreads();
  if (tid == 0) {
    float t = sh[0] + sh[1] + sh[2] + sh[3];
    sscale = rsqrtf(t * (1.0f / DM) + 1e-5f);
  }
  __syncthreads();
  out[(size_t)row * DM + tid] = v * sscale * w[tid];
}

// ---------------- causal depthwise conv (K=4) + bias + silu ----------------
// input: xb = first ED cols of xz (row stride 1024); output xbc (row stride ED)
__global__ __launch_bounds__(256) void conv_silu_k(const float* __restrict__ xz,
                                                   const float* __restrict__ cw,
                                                   const float* __restrict__ cb,
                                                   float* __restrict__ out) {
  const int idx = blockIdx.x * 256 + threadIdx.x;
  if (idx >= MROWS * ED) return;
  const int e = idx & (ED - 1);
  const int row = idx >> 9;
  const int t = row & (SEQ - 1);
  const float4 w = *(const float4*)(cw + e * 4);
  const float* col = xz + e;
  float acc = cb[e];
  const float v0 = (t >= 3) ? col[(size_t)(row - 3) * 1024] : 0.f;
  const float v1 = (t >= 2) ? col[(size_t)(row - 2) * 1024] : 0.f;
  const float v2 = (t >= 1) ? col[(size_t)(row - 1) * 1024] : 0.f;
  const float v3 = col[(size_t)row * 1024];
  acc += v0 * w.x + v1 * w.y + v2 * w.z + v3 * w.w;
  out[idx] = silu_f(acc);
}

// ---------------- delta = softplus(dt @ dt_proj_w^T + dt_proj_b) ----------------
__global__ __launch_bounds__(256) void dt_softplus_k(const float* __restrict__ dbc,
                                                     const float* __restrict__ dtw,
                                                     const float* __restrict__ dtb,
                                                     float* __restrict__ out) {
  __shared__ float sdt[DTR];
  const int row = blockIdx.y;
  const int e = blockIdx.x * 256 + threadIdx.x;
  if (threadIdx.x < DTR) sdt[threadIdx.x] = dbc[(size_t)row * 48 + threadIdx.x];
  __syncthreads();
  const float* w = dtw + (size_t)e * DTR;
  float s = dtb[e];
#pragma unroll
  for (int r = 0; r < DTR; r++) s = fmaf(sdt[r], w[r], s);
  const float sp = fmaxf(s, 0.f) + log1pf(__expf(-fabsf(s)));
  out[(size_t)row * ED + e] = sp;
}

// ---------------- selective scan, fused D*x and silu(z) gating ----------------
// block: 256 threads = 16 e-channels x 16 states; grid (ED/16, B)
// y written into the dead xb half of xz (row stride 1024).
__global__ __launch_bounds__(256) void scan_k(const float* __restrict__ delta,
                                              const float* __restrict__ xbc,
                                              const float* __restrict__ dbc,
                                              float* __restrict__ xz,
                                              const float* __restrict__ A_log,
                                              const float* __restrict__ Dp) {
  __shared__ float sd[32][16], sx[32][16], sz[32][16], sB[32][16], sC[32][16];
  const int tid = threadIdx.x;
  const int n = tid & 15;
  const int eL = tid >> 4;
  const int e0 = blockIdx.x * 16;
  const int e = e0 + eL;
  const int b = blockIdx.y;
  const float Aen = -__expf(A_log[(size_t)e * NST + n]);
  const float De = Dp[e];
  const int base_row = b * SEQ;
  float hst = 0.f;
  for (int t0 = 0; t0 < SEQ; t0 += 32) {
    for (int idx = tid; idx < 512; idx += 256) {
      const int i = idx >> 4, j = idx & 15;
      const size_t r = base_row + t0 + i;
      sd[i][j] = delta[r * ED + e0 + j];
      sx[i][j] = xbc[r * ED + e0 + j];
      sz[i][j] = xz[r * 1024 + ED + e0 + j];
    }
    for (int idx = tid; idx < 1024; idx += 256) {
      const int i = idx >> 5, c = idx & 31;
      const float v = dbc[(size_t)(base_row + t0 + i) * 48 + DTR + c];
      if (c < 16) sB[i][c] = v;
      else sC[i][c - 16] = v;
    }
    __syncthreads();
#pragma unroll 4
    for (int i = 0; i < 32; i++) {
      const float d = sd[i][eL];
      const float xv = sx[i][eL];
      const float dA = __expf(d * Aen);
      hst = dA * hst + (d * xv) * sB[i][n];
      float c = hst * sC[i][n];
      c += __shfl_xor(c, 1, 16);
      c += __shfl_xor(c, 2, 16);
      c += __shfl_xor(c, 4, 16);
      c += __shfl_xor(c, 8, 16);
      if (n == 0) {
        float y = c + De * xv;
        const float zv = sz[i][eL];
        y *= silu_f(zv);
        xz[(size_t)(base_row + t0 + i) * 1024 + e] = y;
      }
    }
    __syncthreads();
  }
}

// ---------------- final decode: sigmoid(h[b, L-1, :] . dec_w + dec_b) ----------------
__global__ __launch_bounds__(64) void decode_k(const float* __restrict__ h,
                                               const float* __restrict__ dw,
                                               const float* __restrict__ db,
                                               float* __restrict__ out) {
  const int b = blockIdx.x;
  const int tid = threadIdx.x;
  const float* row = h + ((size_t)b * SEQ + SEQ - 1) * DM;
  float s = 0.f;
  for (int i = tid; i < DM; i += 64) s = fmaf(row[i], dw[i], s);
#pragma unroll
  for (int off = 32; off; off >>= 1) s += __shfl_xor(s, off, 64);
  if (tid == 0) out[b] = 1.f / (1.f + __expf(-(s + db[0])));
}

extern "C" void kernel_launch(void* const* d_in, const int* in_sizes, int n_in,
                              void* d_out, int out_size, void* d_ws, size_t ws_size,
                              hipStream_t stream) {
  const float* x         = (const float*)d_in[0];
  const float* enc_w     = (const float*)d_in[1];
  const float* enc_b     = (const float*)d_in[2];
  const float* norm_w    = (const float*)d_in[3];
  const float* in_proj_w = (const float*)d_in[4];
  const float* conv_w    = (const float*)d_in[5];
  const float* conv_b    = (const float*)d_in[6];
  const float* x_proj_w  = (const float*)d_in[7];
  const float* dt_proj_w = (const float*)d_in[8];
  const float* dt_proj_b = (const float*)d_in[9];
  const float* A_log     = (const float*)d_in[10];
  const float* D_param   = (const float*)d_in[11];
  const float* out_proj_w= (const float*)d_in[12];
  const float* dec_w     = (const float*)d_in[13];
  const float* dec_b     = (const float*)d_in[14];
  float* out = (float*)d_out;

  float* ws     = (float*)d_ws;
  float* h      = ws;                       // 8192*256
  float* normed = h + (size_t)MROWS * DM;   // 8192*256
  float* xz     = normed + (size_t)MROWS * DM;   // 8192*1024
  float* xbc    = xz + (size_t)MROWS * 1024;     // 8192*512
  float* dbc    = xbc + (size_t)MROWS * ED;      // 8192*48
  float* delta  = dbc + (size_t)MROWS * 48;      // 8192*512

  const dim3 blk(256);

  // encoder: h = x @ enc_w^T + enc_b
  gemm_nt<true, false><<<dim3(DM / 64, MROWS / 64), blk, 0, stream>>>(
      x, enc_w, enc_b, h, MROWS, DM, INDIM, INDIM);

  for (int l = 0; l < 2; l++) {
    rmsnorm_k<<<MROWS, 256, 0, stream>>>(h, norm_w + (size_t)l * DM, normed);
    gemm_nt<false, false><<<dim3(1024 / 64, MROWS / 64), blk, 0, stream>>>(
        normed, in_proj_w + (size_t)l * 1024 * DM, nullptr, xz, MROWS, 1024, DM, DM);
    conv_silu_k<<<(MROWS * ED + 255) / 256, blk, 0, stream>>>(
        xz, conv_w + (size_t)l * ED * 4, conv_b + (size_t)l * ED, xbc);
    gemm_nt<false, false><<<dim3(1, MROWS / 64), blk, 0, stream>>>(
        xbc, x_proj_w + (size_t)l * 48 * ED, nullptr, dbc, MROWS, 48, ED, ED);
    dt_softplus_k<<<dim3(2, MROWS), blk, 0, stream>>>(
        dbc, dt_proj_w + (size_t)l * ED * DTR, dt_proj_b + (size_t)l * ED, delta);
    scan_k<<<dim3(ED / 16, BSZ), blk, 0, stream>>>(
        delta, xbc, dbc, xz, A_log + (size_t)l * ED * NST, D_param + (size_t)l * ED);
    gemm_nt<false, true><<<dim3(DM / 64, MROWS / 64), blk, 0, stream>>>(
        xz, out_proj_w + (size_t)l * DM * ED, nullptr, h, MROWS, DM, ED, 1024);
  }

  decode_k<<<4, 64, 0, stream>>>(h, dec_w, dec_b, out);
}

// Round 2
// 691.502 us; speedup vs baseline: 2.6908x; 2.6908x over previous
//
#include <hip/hip_runtime.h>
#include <math.h>

#define BSZ 4
#define SEQ 2048
#define INDIM 32
#define DM 256
#define ED 512
#define NST 16
#define DTR 16
#define MROWS (BSZ * SEQ) /* 8192 */
#define CH 64              /* chunks for the scan */
#define LC (SEQ / CH)      /* 32 timesteps per chunk */

__device__ __forceinline__ float silu_f(float x) { return x / (1.f + __expf(-x)); }

// ---------------- generic NT GEMM: C[m,n] = sum_k A[m,k(lda)] * B[n,k]  ----------------
template <bool BIAS, bool ACCUM>
__global__ __launch_bounds__(256) void gemm_nt(const float* __restrict__ A,
                                               const float* __restrict__ B,
                                               const float* __restrict__ bias,
                                               float* __restrict__ C,
                                               int M, int N, int K, int lda) {
  __shared__ float As[16][65];
  __shared__ float Bs[16][65];
  const int tid = threadIdx.x;
  const int m0 = blockIdx.y * 64;
  const int n0 = blockIdx.x * 64;
  const int tm = tid & 15, tn = tid >> 4;
  const int lrow = tid >> 2;
  const int lk = (tid & 3) << 2;
  float acc[4][4] = {};
  for (int k0 = 0; k0 < K; k0 += 16) {
    {
      const float4 a = *(const float4*)(A + (size_t)(m0 + lrow) * lda + k0 + lk);
      As[lk + 0][lrow] = a.x; As[lk + 1][lrow] = a.y;
      As[lk + 2][lrow] = a.z; As[lk + 3][lrow] = a.w;
    }
    {
      float4 b = make_float4(0.f, 0.f, 0.f, 0.f);
      if (n0 + lrow < N) b = *(const float4*)(B + (size_t)(n0 + lrow) * K + k0 + lk);
      Bs[lk + 0][lrow] = b.x; Bs[lk + 1][lrow] = b.y;
      Bs[lk + 2][lrow] = b.z; Bs[lk + 3][lrow] = b.w;
    }
    __syncthreads();
#pragma unroll
    for (int k = 0; k < 16; k++) {
      float a4[4], b4[4];
#pragma unroll
      for (int i = 0; i < 4; i++) a4[i] = As[k][tm * 4 + i];
#pragma unroll
      for (int j = 0; j < 4; j++) b4[j] = Bs[k][tn * 4 + j];
#pragma unroll
      for (int i = 0; i < 4; i++)
#pragma unroll
        for (int j = 0; j < 4; j++) acc[i][j] = fmaf(a4[i], b4[j], acc[i][j]);
    }
    __syncthreads();
  }
#pragma unroll
  for (int i = 0; i < 4; i++) {
    const int m = m0 + tm * 4 + i;
#pragma unroll
    for (int j = 0; j < 4; j++) {
      const int n = n0 + tn * 4 + j;
      if (n < N) {
        float v = acc[i][j];
        if (BIAS) v += bias[n];
        float* p = C + (size_t)m * N + n;
        if (ACCUM) v += *p;
        *p = v;
      }
    }
  }
}

// ---------------- rmsnorm over DM=256 ----------------
__global__ __launch_bounds__(256) void rmsnorm_k(const float* __restrict__ h,
                                                 const float* __restrict__ w,
                                                 float* __restrict__ out) {
  __shared__ float sh[4];
  __shared__ float sscale;
  const int row = blockIdx.x;
  const int tid = threadIdx.x;
  const float v = h[(size_t)row * DM + tid];
  float s = v * v;
#pragma unroll
  for (int off = 32; off; off >>= 1) s += __shfl_xor(s, off, 64);
  if ((tid & 63) == 0) sh[tid >> 6] = s;
  __syncthreads();
  if (tid == 0) {
    float t = sh[0] + sh[1] + sh[2] + sh[3];
    sscale = rsqrtf(t * (1.0f / DM) + 1e-5f);
  }
  __syncthreads();
  out[(size_t)row * DM + tid] = v * sscale * w[tid];
}

// ---------------- causal depthwise conv (K=4) + bias + silu ----------------
__global__ __launch_bounds__(256) void conv_silu_k(const float* __restrict__ xz,
                                                   const float* __restrict__ cw,
                                                   const float* __restrict__ cb,
                                                   float* __restrict__ out) {
  const int idx = blockIdx.x * 256 + threadIdx.x;
  if (idx >= MROWS * ED) return;
  const int e = idx & (ED - 1);
  const int row = idx >> 9;
  const int t = row & (SEQ - 1);
  const float4 w = *(const float4*)(cw + e * 4);
  const float* col = xz + e;
  float acc = cb[e];
  const float v0 = (t >= 3) ? col[(size_t)(row - 3) * 1024] : 0.f;
  const float v1 = (t >= 2) ? col[(size_t)(row - 2) * 1024] : 0.f;
  const float v2 = (t >= 1) ? col[(size_t)(row - 1) * 1024] : 0.f;
  const float v3 = col[(size_t)row * 1024];
  acc += v0 * w.x + v1 * w.y + v2 * w.z + v3 * w.w;
  out[idx] = silu_f(acc);
}

// ---------------- delta = softplus(dt @ dt_proj_w^T + dt_proj_b) ----------------
__global__ __launch_bounds__(256) void dt_softplus_k(const float* __restrict__ dbc,
                                                     const float* __restrict__ dtw,
                                                     const float* __restrict__ dtb,
                                                     float* __restrict__ out) {
  __shared__ float sdt[DTR];
  const int row = blockIdx.y;
  const int e = blockIdx.x * 256 + threadIdx.x;
  if (threadIdx.x < DTR) sdt[threadIdx.x] = dbc[(size_t)row * 48 + threadIdx.x];
  __syncthreads();
  const float* w = dtw + (size_t)e * DTR;
  float s = dtb[e];
#pragma unroll
  for (int r = 0; r < DTR; r++) s = fmaf(sdt[r], w[r], s);
  const float sp = fmaxf(s, 0.f) + log1pf(__expf(-fabsf(s)));
  out[(size_t)row * ED + e] = sp;
}

// ================= chunked selective scan =================
// pass1: per-chunk local scan from h=0. Stores h_end[c][b][e][n] and S=sum(delta)
// (S stashed in the dead x-half of xz rows 0..255: xz[(c*BSZ+b)*1024 + e]).
__global__ __launch_bounds__(256) void scan_pass1(const float* __restrict__ delta,
                                                  const float* __restrict__ xbc,
                                                  const float* __restrict__ dbc,
                                                  float* __restrict__ xz,
                                                  float* __restrict__ hend,
                                                  const float* __restrict__ A_log) {
  __shared__ float sB[LC][16];
  const int tid = threadIdx.x;
  const int e = blockIdx.x * 256 + tid;
  const int c = blockIdx.y;
  const int b = blockIdx.z;
  const int row0 = b * SEQ + c * LC;
  float Aen[16];
  {
    const float4* ap = (const float4*)(A_log + (size_t)e * 16);
#pragma unroll
    for (int q = 0; q < 4; q++) {
      float4 v = ap[q];
      Aen[4 * q + 0] = -__expf(v.x); Aen[4 * q + 1] = -__expf(v.y);
      Aen[4 * q + 2] = -__expf(v.z); Aen[4 * q + 3] = -__expf(v.w);
    }
  }
  for (int idx = tid; idx < LC * 16; idx += 256)
    sB[idx >> 4][idx & 15] = dbc[(size_t)(row0 + (idx >> 4)) * 48 + DTR + (idx & 15)];
  __syncthreads();
  const float* dp = delta + (size_t)row0 * ED + e;
  const float* xp = xbc + (size_t)row0 * ED + e;
  float h[16];
#pragma unroll
  for (int n = 0; n < 16; n++) h[n] = 0.f;
  float S = 0.f;
  float d = dp[0], xv = xp[0];
  for (int t = 0; t < LC; t++) {
    const int tn = (t + 1 < LC) ? t + 1 : t;
    const float dnx = dp[(size_t)tn * ED];
    const float xnx = xp[(size_t)tn * ED];
    S += d;
    const float dx = d * xv;
    const float4* bp = (const float4*)sB[t];
    const float4 B0 = bp[0], B1 = bp[1], B2 = bp[2], B3 = bp[3];
    const float Bv[16] = {B0.x, B0.y, B0.z, B0.w, B1.x, B1.y, B1.z, B1.w,
                          B2.x, B2.y, B2.z, B2.w, B3.x, B3.y, B3.z, B3.w};
#pragma unroll
    for (int n = 0; n < 16; n++) h[n] = __expf(d * Aen[n]) * h[n] + dx * Bv[n];
    d = dnx; xv = xnx;
  }
  float4* hp = (float4*)(hend + ((size_t)(c * BSZ + b) * ED + e) * 16);
#pragma unroll
  for (int q = 0; q < 4; q++)
    hp[q] = make_float4(h[4 * q], h[4 * q + 1], h[4 * q + 2], h[4 * q + 3]);
  xz[(size_t)(c * BSZ + b) * 1024 + e] = S;
}

// mid: sequential over chunks; converts hend -> hin in place.
// hin[c] = exp(A*S[c-1]) * hin[c-1] + hend[c-1], hin[0]=0.
__global__ __launch_bounds__(256) void scan_mid(float* __restrict__ hend,
                                                const float* __restrict__ xz,
                                                const float* __restrict__ A_log) {
  const int idx = blockIdx.x * 256 + threadIdx.x; // B*ED*NST = 32768
  const int en = idx & 8191;                      // e*16+n
  const int b = idx >> 13;
  const int e = en >> 4;
  const float A = -__expf(A_log[en]);
  float h = 0.f;
#pragma unroll 4
  for (int c = 0; c < CH; c++) {
    const size_t base = (size_t)(c * BSZ + b) * 8192 + en;
    const float he = hend[base];
    const float Sv = xz[(size_t)(c * BSZ + b) * 1024 + e];
    hend[base] = h;
    h = __expf(A * Sv) * h + he;
  }
}

// pass2: re-scan each chunk from hin, fused y = C.h + D*x, silu(z) gating.
// y written into the x-half of xz.
__global__ __launch_bounds__(256) void scan_pass2(const float* __restrict__ delta,
                                                  const float* __restrict__ xbc,
                                                  const float* __restrict__ dbc,
                                                  float* __restrict__ xz,
                                                  const float* __restrict__ hin,
                                                  const float* __restrict__ A_log,
                                                  const float* __restrict__ Dp) {
  __shared__ float sB[LC][16];
  __shared__ float sC[LC][16];
  const int tid = threadIdx.x;
  const int e = blockIdx.x * 256 + tid;
  const int c = blockIdx.y;
  const int b = blockIdx.z;
  const int row0 = b * SEQ + c * LC;
  float Aen[16];
  {
    const float4* ap = (const float4*)(A_log + (size_t)e * 16);
#pragma unroll
    for (int q = 0; q < 4; q++) {
      float4 v = ap[q];
      Aen[4 * q + 0] = -__expf(v.x); Aen[4 * q + 1] = -__expf(v.y);
      Aen[4 * q + 2] = -__expf(v.z); Aen[4 * q + 3] = -__expf(v.w);
    }
  }
  for (int idx = tid; idx < LC * 32; idx += 256) {
    const int i = idx >> 5, j = idx & 31;
    const float v = dbc[(size_t)(row0 + i) * 48 + DTR + j];
    if (j < 16) sB[i][j] = v; else sC[i][j - 16] = v;
  }
  __syncthreads();
  float h[16];
  {
    const float4* hp = (const float4*)(hin + ((size_t)(c * BSZ + b) * ED + e) * 16);
#pragma unroll
    for (int q = 0; q < 4; q++) {
      float4 v = hp[q];
      h[4 * q + 0] = v.x; h[4 * q + 1] = v.y; h[4 * q + 2] = v.z; h[4 * q + 3] = v.w;
    }
  }
  const float De = Dp[e];
  const float* dp = delta + (size_t)row0 * ED + e;
  const float* xp = xbc + (size_t)row0 * ED + e;
  float* yzp = xz + (size_t)row0 * 1024 + e;
  float d = dp[0], xv = xp[0], zv = yzp[ED];
  for (int t = 0; t < LC; t++) {
    const int tn = (t + 1 < LC) ? t + 1 : t;
    const float dnx = dp[(size_t)tn * ED];
    const float xnx = xp[(size_t)tn * ED];
    const float znx = yzp[(size_t)tn * 1024 + ED];
    const float dx = d * xv;
    const float4* bp = (const float4*)sB[t];
    const float4 B0 = bp[0], B1 = bp[1], B2 = bp[2], B3 = bp[3];
    const float Bv[16] = {B0.x, B0.y, B0.z, B0.w, B1.x, B1.y, B1.z, B1.w,
                          B2.x, B2.y, B2.z, B2.w, B3.x, B3.y, B3.z, B3.w};
    const float4* cp = (const float4*)sC[t];
    const float4 C0 = cp[0], C1 = cp[1], C2 = cp[2], C3 = cp[3];
    const float Cv[16] = {C0.x, C0.y, C0.z, C0.w, C1.x, C1.y, C1.z, C1.w,
                          C2.x, C2.y, C2.z, C2.w, C3.x, C3.y, C3.z, C3.w};
    float y0 = 0.f, y1 = 0.f, y2 = 0.f, y3 = 0.f;
#pragma unroll
    for (int n = 0; n < 16; n++) {
      h[n] = __expf(d * Aen[n]) * h[n] + dx * Bv[n];
      if ((n & 3) == 0) y0 = fmaf(h[n], Cv[n], y0);
      else if ((n & 3) == 1) y1 = fmaf(h[n], Cv[n], y1);
      else if ((n & 3) == 2) y2 = fmaf(h[n], Cv[n], y2);
      else y3 = fmaf(h[n], Cv[n], y3);
    }
    float y = ((y0 + y1) + (y2 + y3)) + De * xv;
    y *= silu_f(zv);
    yzp[(size_t)t * 1024] = y;
    d = dnx; xv = xnx; zv = znx;
  }
}

// ---------------- final decode ----------------
__global__ __launch_bounds__(64) void decode_k(const float* __restrict__ h,
                                               const float* __restrict__ dw,
                                               const float* __restrict__ db,
                                               float* __restrict__ out) {
  const int b = blockIdx.x;
  const int tid = threadIdx.x;
  const float* row = h + ((size_t)b * SEQ + SEQ - 1) * DM;
  float s = 0.f;
  for (int i = tid; i < DM; i += 64) s = fmaf(row[i], dw[i], s);
#pragma unroll
  for (int off = 32; off; off >>= 1) s += __shfl_xor(s, off, 64);
  if (tid == 0) out[b] = 1.f / (1.f + __expf(-(s + db[0])));
}

extern "C" void kernel_launch(void* const* d_in, const int* in_sizes, int n_in,
                              void* d_out, int out_size, void* d_ws, size_t ws_size,
                              hipStream_t stream) {
  const float* x         = (const float*)d_in[0];
  const float* enc_w     = (const float*)d_in[1];
  const float* enc_b     = (const float*)d_in[2];
  const float* norm_w    = (const float*)d_in[3];
  const float* in_proj_w = (const float*)d_in[4];
  const float* conv_w    = (const float*)d_in[5];
  const float* conv_b    = (const float*)d_in[6];
  const float* x_proj_w  = (const float*)d_in[7];
  const float* dt_proj_w = (const float*)d_in[8];
  const float* dt_proj_b = (const float*)d_in[9];
  const float* A_log     = (const float*)d_in[10];
  const float* D_param   = (const float*)d_in[11];
  const float* out_proj_w= (const float*)d_in[12];
  const float* dec_w     = (const float*)d_in[13];
  const float* dec_b     = (const float*)d_in[14];
  float* out = (float*)d_out;

  float* ws     = (float*)d_ws;
  float* h      = ws;                            // 8192*256
  float* normed = h + (size_t)MROWS * DM;        // 8192*256 (aliased as hend/hin during scan)
  float* xz     = normed + (size_t)MROWS * DM;   // 8192*1024
  float* xbc    = xz + (size_t)MROWS * 1024;     // 8192*512
  float* dbc    = xbc + (size_t)MROWS * ED;      // 8192*48
  float* delta  = dbc + (size_t)MROWS * 48;      // 8192*512
  float* hend   = normed;                        // CH*BSZ*ED*NST = 2M floats, exact fit

  const dim3 blk(256);

  gemm_nt<true, false><<<dim3(DM / 64, MROWS / 64), blk, 0, stream>>>(
      x, enc_w, enc_b, h, MROWS, DM, INDIM, INDIM);

  for (int l = 0; l < 2; l++) {
    const float* Al = A_log + (size_t)l * ED * NST;
    rmsnorm_k<<<MROWS, 256, 0, stream>>>(h, norm_w + (size_t)l * DM, normed);
    gemm_nt<false, false><<<dim3(1024 / 64, MROWS / 64), blk, 0, stream>>>(
        normed, in_proj_w + (size_t)l * 1024 * DM, nullptr, xz, MROWS, 1024, DM, DM);
    conv_silu_k<<<(MROWS * ED + 255) / 256, blk, 0, stream>>>(
        xz, conv_w + (size_t)l * ED * 4, conv_b + (size_t)l * ED, xbc);
    gemm_nt<false, false><<<dim3(1, MROWS / 64), blk, 0, stream>>>(
        xbc, x_proj_w + (size_t)l * 48 * ED, nullptr, dbc, MROWS, 48, ED, ED);
    dt_softplus_k<<<dim3(2, MROWS), blk, 0, stream>>>(
        dbc, dt_proj_w + (size_t)l * ED * DTR, dt_proj_b + (size_t)l * ED, delta);
    scan_pass1<<<dim3(ED / 256, CH, BSZ), blk, 0, stream>>>(
        delta, xbc, dbc, xz, hend, Al);
    scan_mid<<<(BSZ * ED * NST) / 256, blk, 0, stream>>>(hend, xz, Al);
    scan_pass2<<<dim3(ED / 256, CH, BSZ), blk, 0, stream>>>(
        delta, xbc, dbc, xz, hend, Al, D_param + (size_t)l * ED);
    gemm_nt<false, true><<<dim3(DM / 64, MROWS / 64), blk, 0, stream>>>(
        xz, out_proj_w + (size_t)l * DM * ED, nullptr, h, MROWS, DM, ED, 1024);
  }

  decode_k<<<4, 64, 0, stream>>>(h, dec_w, dec_b, out);
}

// Round 4
// 408.321 us; speedup vs baseline: 4.5570x; 1.6935x over previous
//
#include <hip/hip_runtime.h>
#include <math.h>

#define BSZ 4
#define SEQ 2048
#define INDIM 32
#define DM 256
#define ED 512
#define NST 16
#define DTR 16
#define MROWS (BSZ * SEQ) /* 8192 */
#define CH 64              /* chunks for the scan */
#define LC (SEQ / CH)      /* 32 timesteps per chunk */

typedef unsigned short u16;
typedef __bf16 bf16x8 __attribute__((ext_vector_type(8)));
typedef float f32x4 __attribute__((ext_vector_type(4)));

__device__ __forceinline__ float silu_f(float x) { return x / (1.f + __expf(-x)); }

__device__ __forceinline__ u16 f2bf(float x) {
  union { float f; unsigned u; } c; c.f = x;
  return (u16)((c.u + 0x7FFF + ((c.u >> 16) & 1)) >> 16);
}
__device__ __forceinline__ float bf2f(u16 v) {
  union { unsigned u; float f; } c; c.u = ((unsigned)v) << 16;
  return c.f;
}

// ---------------- bf16 MFMA GEMM: C[m,n] (+)= sum_k A16[m,k]*B16[n,k] ----------------
// 128x128 tile, 4 waves (2x2), each wave 64x64 via 4x4 mfma_f32_16x16x32_bf16.
// M multiple of 128; N guarded; K multiple of 32.
template <bool ACCUM>
__global__ __launch_bounds__(256) void gemm_bf16(const u16* __restrict__ A,
                                                 const u16* __restrict__ B,
                                                 float* __restrict__ C,
                                                 int M, int N, int K,
                                                 int lda, int ldc) {
  __shared__ u16 As[128][40];
  __shared__ u16 Bs[128][40];
  const int tid = threadIdx.x;
  const int m0 = blockIdx.y * 128;
  const int n0 = blockIdx.x * 128;
  const int wid = tid >> 6;
  const int lane = tid & 63;
  const int wm = (wid >> 1) * 64, wn = (wid & 1) * 64;
  const int l15 = lane & 15, l4 = lane >> 4;
  const int arow = tid >> 1;           // 0..127
  const int ak = (tid & 1) * 16;       // 0 or 16 (u16 elements)
  f32x4 acc[4][4];
  const f32x4 zero = {0.f, 0.f, 0.f, 0.f};
#pragma unroll
  for (int i = 0; i < 4; i++)
#pragma unroll
    for (int j = 0; j < 4; j++) acc[i][j] = zero;

  for (int k0 = 0; k0 < K; k0 += 32) {
    {
      // each thread stages 16 u16 (32B) of A and of B: two int4 (16B) loads each
      const u16* ap = A + (size_t)(m0 + arow) * lda + k0 + ak;
      *(int4*)&As[arow][ak]     = *(const int4*)(ap);
      *(int4*)&As[arow][ak + 8] = *(const int4*)(ap + 8);
      int4 bv0 = {0, 0, 0, 0}, bv1 = {0, 0, 0, 0};
      if (n0 + arow < N) {
        const u16* bp = B + (size_t)(n0 + arow) * K + k0 + ak;
        bv0 = *(const int4*)(bp);
        bv1 = *(const int4*)(bp + 8);
      }
      *(int4*)&Bs[arow][ak]     = bv0;
      *(int4*)&Bs[arow][ak + 8] = bv1;
    }
    __syncthreads();
    bf16x8 af[4], bfr[4];
#pragma unroll
    for (int i = 0; i < 4; i++) {
      af[i]  = *(const bf16x8*)&As[wm + i * 16 + l15][l4 * 8];
      bfr[i] = *(const bf16x8*)&Bs[wn + i * 16 + l15][l4 * 8];
    }
#pragma unroll
    for (int i = 0; i < 4; i++)
#pragma unroll
      for (int j = 0; j < 4; j++)
        acc[i][j] = __builtin_amdgcn_mfma_f32_16x16x32_bf16(af[i], bfr[j], acc[i][j], 0, 0, 0);
    __syncthreads();
  }
#pragma unroll
  for (int i = 0; i < 4; i++) {
    const int mb = m0 + wm + i * 16 + l4 * 4;
#pragma unroll
    for (int j = 0; j < 4; j++) {
      const int n = n0 + wn + j * 16 + l15;
      if (n < N) {
        float* p = C + (size_t)mb * ldc + n;
#pragma unroll
        for (int r = 0; r < 4; r++) {
          float v = acc[i][j][r];
          if (ACCUM) v += p[(size_t)r * ldc];
          p[(size_t)r * ldc] = v;
        }
      }
    }
  }
}

// ---------------- fp32 NT GEMM (encoder only: K=32) ----------------
template <bool BIAS, bool ACCUM>
__global__ __launch_bounds__(256) void gemm_nt(const float* __restrict__ A,
                                               const float* __restrict__ B,
                                               const float* __restrict__ bias,
                                               float* __restrict__ C,
                                               int M, int N, int K, int lda) {
  __shared__ float As[16][65];
  __shared__ float Bs[16][65];
  const int tid = threadIdx.x;
  const int m0 = blockIdx.y * 64;
  const int n0 = blockIdx.x * 64;
  const int tm = tid & 15, tn = tid >> 4;
  const int lrow = tid >> 2;
  const int lk = (tid & 3) << 2;
  float acc[4][4] = {};
  for (int k0 = 0; k0 < K; k0 += 16) {
    {
      const float4 a = *(const float4*)(A + (size_t)(m0 + lrow) * lda + k0 + lk);
      As[lk + 0][lrow] = a.x; As[lk + 1][lrow] = a.y;
      As[lk + 2][lrow] = a.z; As[lk + 3][lrow] = a.w;
    }
    {
      float4 b = make_float4(0.f, 0.f, 0.f, 0.f);
      if (n0 + lrow < N) b = *(const float4*)(B + (size_t)(n0 + lrow) * K + k0 + lk);
      Bs[lk + 0][lrow] = b.x; Bs[lk + 1][lrow] = b.y;
      Bs[lk + 2][lrow] = b.z; Bs[lk + 3][lrow] = b.w;
    }
    __syncthreads();
#pragma unroll
    for (int k = 0; k < 16; k++) {
      float a4[4], b4[4];
#pragma unroll
      for (int i = 0; i < 4; i++) a4[i] = As[k][tm * 4 + i];
#pragma unroll
      for (int j = 0; j < 4; j++) b4[j] = Bs[k][tn * 4 + j];
#pragma unroll
      for (int i = 0; i < 4; i++)
#pragma unroll
        for (int j = 0; j < 4; j++) acc[i][j] = fmaf(a4[i], b4[j], acc[i][j]);
    }
    __syncthreads();
  }
#pragma unroll
  for (int i = 0; i < 4; i++) {
    const int m = m0 + tm * 4 + i;
#pragma unroll
    for (int j = 0; j < 4; j++) {
      const int n = n0 + tn * 4 + j;
      if (n < N) {
        float v = acc[i][j];
        if (BIAS) v += bias[n];
        float* p = C + (size_t)m * N + n;
        if (ACCUM) v += *p;
        *p = v;
      }
    }
  }
}

// ---------------- weight fp32 -> bf16 conversion (all layers, one launch) ----------------
#define S_IN (2 * 1024 * 256)
#define S_OUT (2 * 256 * 512)
#define S_XP (2 * 48 * 512)
__global__ __launch_bounds__(256) void cvt_weights_k(const float* __restrict__ w1,
                                                     const float* __restrict__ w2,
                                                     const float* __restrict__ w3,
                                                     u16* __restrict__ o1,
                                                     u16* __restrict__ o2,
                                                     u16* __restrict__ o3) {
  const int i = blockIdx.x * 256 + threadIdx.x;
  if (i < S_IN) o1[i] = f2bf(w1[i]);
  else if (i < S_IN + S_OUT) o2[i - S_IN] = f2bf(w2[i - S_IN]);
  else if (i < S_IN + S_OUT + S_XP) o3[i - S_IN - S_OUT] = f2bf(w3[i - S_IN - S_OUT]);
}

// ---------------- rmsnorm over DM=256, bf16 output ----------------
__global__ __launch_bounds__(256) void rmsnorm_k(const float* __restrict__ h,
                                                 const float* __restrict__ w,
                                                 u16* __restrict__ out16) {
  __shared__ float sh[4];
  __shared__ float sscale;
  const int row = blockIdx.x;
  const int tid = threadIdx.x;
  const float v = h[(size_t)row * DM + tid];
  float s = v * v;
#pragma unroll
  for (int off = 32; off; off >>= 1) s += __shfl_xor(s, off, 64);
  if ((tid & 63) == 0) sh[tid >> 6] = s;
  __syncthreads();
  if (tid == 0) {
    float t = sh[0] + sh[1] + sh[2] + sh[3];
    sscale = rsqrtf(t * (1.0f / DM) + 1e-5f);
  }
  __syncthreads();
  out16[(size_t)row * DM + tid] = f2bf(v * sscale * w[tid]);
}

// ---------------- causal depthwise conv (K=4) + bias + silu, bf16 output ----------------
__global__ __launch_bounds__(256) void conv_silu_k(const float* __restrict__ xz,
                                                   const float* __restrict__ cw,
                                                   const float* __restrict__ cb,
                                                   u16* __restrict__ out16) {
  const int idx = blockIdx.x * 256 + threadIdx.x;
  if (idx >= MROWS * ED) return;
  const int e = idx & (ED - 1);
  const int row = idx >> 9;
  const int t = row & (SEQ - 1);
  const float4 w = *(const float4*)(cw + e * 4);
  const float* col = xz + e;
  float acc = cb[e];
  const float v0 = (t >= 3) ? col[(size_t)(row - 3) * 1024] : 0.f;
  const float v1 = (t >= 2) ? col[(size_t)(row - 2) * 1024] : 0.f;
  const float v2 = (t >= 1) ? col[(size_t)(row - 1) * 1024] : 0.f;
  const float v3 = col[(size_t)row * 1024];
  acc += v0 * w.x + v1 * w.y + v2 * w.z + v3 * w.w;
  out16[idx] = f2bf(silu_f(acc));
}

// ---------------- delta = softplus(dt @ dt_proj_w^T + dt_proj_b) ----------------
__global__ __launch_bounds__(256) void dt_softplus_k(const float* __restrict__ dbc,
                                                     const float* __restrict__ dtw,
                                                     const float* __restrict__ dtb,
                                                     float* __restrict__ out) {
  __shared__ float sdt[DTR];
  const int row = blockIdx.y;
  const int e = blockIdx.x * 256 + threadIdx.x;
  if (threadIdx.x < DTR) sdt[threadIdx.x] = dbc[(size_t)row * 48 + threadIdx.x];
  __syncthreads();
  const float* w = dtw + (size_t)e * DTR;
  float s = dtb[e];
#pragma unroll
  for (int r = 0; r < DTR; r++) s = fmaf(sdt[r], w[r], s);
  const float sp = fmaxf(s, 0.f) + log1pf(__expf(-fabsf(s)));
  out[(size_t)row * ED + e] = sp;
}

// ================= chunked selective scan =================
// pass1: per-chunk local scan from h=0 -> h_end[c][b][e][n], S=sum(delta)
// (S stashed in xz x-half rows 0..255: xz[(c*BSZ+b)*1024 + e]).
__global__ __launch_bounds__(256) void scan_pass1(const float* __restrict__ delta,
                                                  const u16* __restrict__ xbc16,
                                                  const float* __restrict__ dbc,
                                                  float* __restrict__ xz,
                                                  float* __restrict__ hend,
                                                  const float* __restrict__ A_log) {
  __shared__ float sB[LC][16];
  const int tid = threadIdx.x;
  const int e = blockIdx.x * 256 + tid;
  const int c = blockIdx.y;
  const int b = blockIdx.z;
  const int row0 = b * SEQ + c * LC;
  float Aen[16];
  {
    const float4* ap = (const float4*)(A_log + (size_t)e * 16);
#pragma unroll
    for (int q = 0; q < 4; q++) {
      float4 v = ap[q];
      Aen[4 * q + 0] = -__expf(v.x); Aen[4 * q + 1] = -__expf(v.y);
      Aen[4 * q + 2] = -__expf(v.z); Aen[4 * q + 3] = -__expf(v.w);
    }
  }
  for (int idx = tid; idx < LC * 16; idx += 256)
    sB[idx >> 4][idx & 15] = dbc[(size_t)(row0 + (idx >> 4)) * 48 + DTR + (idx & 15)];
  __syncthreads();
  const float* dp = delta + (size_t)row0 * ED + e;
  const u16* xp = xbc16 + (size_t)row0 * ED + e;
  float h[16];
#pragma unroll
  for (int n = 0; n < 16; n++) h[n] = 0.f;
  float S = 0.f;
  float d = dp[0], xv = bf2f(xp[0]);
  for (int t = 0; t < LC; t++) {
    const int tn = (t + 1 < LC) ? t + 1 : t;
    const float dnx = dp[(size_t)tn * ED];
    const float xnx = bf2f(xp[(size_t)tn * ED]);
    S += d;
    const float dx = d * xv;
    const float4* bp = (const float4*)sB[t];
    const float4 B0 = bp[0], B1 = bp[1], B2 = bp[2], B3 = bp[3];
    const float Bv[16] = {B0.x, B0.y, B0.z, B0.w, B1.x, B1.y, B1.z, B1.w,
                          B2.x, B2.y, B2.z, B2.w, B3.x, B3.y, B3.z, B3.w};
#pragma unroll
    for (int n = 0; n < 16; n++) h[n] = __expf(d * Aen[n]) * h[n] + dx * Bv[n];
    d = dnx; xv = xnx;
  }
  float4* hp = (float4*)(hend + ((size_t)(c * BSZ + b) * ED + e) * 16);
#pragma unroll
  for (int q = 0; q < 4; q++)
    hp[q] = make_float4(h[4 * q], h[4 * q + 1], h[4 * q + 2], h[4 * q + 3]);
  xz[(size_t)(c * BSZ + b) * 1024 + e] = S;
}

// mid: sequential over chunks; converts hend -> hin in place.
__global__ __launch_bounds__(256) void scan_mid(float* __restrict__ hend,
                                                const float* __restrict__ xz,
                                                const float* __restrict__ A_log) {
  const int idx = blockIdx.x * 256 + threadIdx.x; // B*ED*NST = 32768
  const int en = idx & 8191;
  const int b = idx >> 13;
  const int e = en >> 4;
  const float A = -__expf(A_log[en]);
  float h = 0.f;
#pragma unroll 4
  for (int c = 0; c < CH; c++) {
    const size_t base = (size_t)(c * BSZ + b) * 8192 + en;
    const float he = hend[base];
    const float Sv = xz[(size_t)(c * BSZ + b) * 1024 + e];
    hend[base] = h;
    h = __expf(A * Sv) * h + he;
  }
}

// pass2: re-scan each chunk from hin; y = C.h + D*x, gated by silu(z);
// y written as bf16 into the first 1024 bytes of each xz row (dead x-half).
__global__ __launch_bounds__(256) void scan_pass2(const float* __restrict__ delta,
                                                  const u16* __restrict__ xbc16,
                                                  const float* __restrict__ dbc,
                                                  float* __restrict__ xz,
                                                  const float* __restrict__ hin,
                                                  const float* __restrict__ A_log,
                                                  const float* __restrict__ Dp) {
  __shared__ float sB[LC][16];
  __shared__ float sC[LC][16];
  const int tid = threadIdx.x;
  const int e = blockIdx.x * 256 + tid;
  const int c = blockIdx.y;
  const int b = blockIdx.z;
  const int row0 = b * SEQ + c * LC;
  float Aen[16];
  {
    const float4* ap = (const float4*)(A_log + (size_t)e * 16);
#pragma unroll
    for (int q = 0; q < 4; q++) {
      float4 v = ap[q];
      Aen[4 * q + 0] = -__expf(v.x); Aen[4 * q + 1] = -__expf(v.y);
      Aen[4 * q + 2] = -__expf(v.z); Aen[4 * q + 3] = -__expf(v.w);
    }
  }
  for (int idx = tid; idx < LC * 32; idx += 256) {
    const int i = idx >> 5, j = idx & 31;
    const float v = dbc[(size_t)(row0 + i) * 48 + DTR + j];
    if (j < 16) sB[i][j] = v; else sC[i][j - 16] = v;
  }
  __syncthreads();
  float h[16];
  {
    const float4* hp = (const float4*)(hin + ((size_t)(c * BSZ + b) * ED + e) * 16);
#pragma unroll
    for (int q = 0; q < 4; q++) {
      float4 v = hp[q];
      h[4 * q + 0] = v.x; h[4 * q + 1] = v.y; h[4 * q + 2] = v.z; h[4 * q + 3] = v.w;
    }
  }
  const float De = Dp[e];
  const float* dp = delta + (size_t)row0 * ED + e;
  const u16* xp = xbc16 + (size_t)row0 * ED + e;
  const float* zp = xz + (size_t)row0 * 1024 + ED + e;
  u16* yw = ((u16*)xz) + (size_t)row0 * 2048 + e;
  float d = dp[0], xv = bf2f(xp[0]), zv = zp[0];
  for (int t = 0; t < LC; t++) {
    const int tn = (t + 1 < LC) ? t + 1 : t;
    const float dnx = dp[(size_t)tn * ED];
    const float xnx = bf2f(xp[(size_t)tn * ED]);
    const float znx = zp[(size_t)tn * 1024];
    const float dx = d * xv;
    const float4* bp = (const float4*)sB[t];
    const float4 B0 = bp[0], B1 = bp[1], B2 = bp[2], B3 = bp[3];
    const float Bv[16] = {B0.x, B0.y, B0.z, B0.w, B1.x, B1.y, B1.z, B1.w,
                          B2.x, B2.y, B2.z, B2.w, B3.x, B3.y, B3.z, B3.w};
    const float4* cp = (const float4*)sC[t];
    const float4 C0 = cp[0], C1 = cp[1], C2 = cp[2], C3 = cp[3];
    const float Cv[16] = {C0.x, C0.y, C0.z, C0.w, C1.x, C1.y, C1.z, C1.w,
                          C2.x, C2.y, C2.z, C2.w, C3.x, C3.y, C3.z, C3.w};
    float y0 = 0.f, y1 = 0.f, y2 = 0.f, y3 = 0.f;
#pragma unroll
    for (int n = 0; n < 16; n++) {
      h[n] = __expf(d * Aen[n]) * h[n] + dx * Bv[n];
      if ((n & 3) == 0) y0 = fmaf(h[n], Cv[n], y0);
      else if ((n & 3) == 1) y1 = fmaf(h[n], Cv[n], y1);
      else if ((n & 3) == 2) y2 = fmaf(h[n], Cv[n], y2);
      else y3 = fmaf(h[n], Cv[n], y3);
    }
    float y = ((y0 + y1) + (y2 + y3)) + De * xv;
    y *= silu_f(zv);
    yw[(size_t)t * 2048] = f2bf(y);
    d = dnx; xv = xnx; zv = znx;
  }
}

// ---------------- final decode ----------------
__global__ __launch_bounds__(64) void decode_k(const float* __restrict__ h,
                                               const float* __restrict__ dw,
                                               const float* __restrict__ db,
                                               float* __restrict__ out) {
  const int b = blockIdx.x;
  const int tid = threadIdx.x;
  const float* row = h + ((size_t)b * SEQ + SEQ - 1) * DM;
  float s = 0.f;
  for (int i = tid; i < DM; i += 64) s = fmaf(row[i], dw[i], s);
#pragma unroll
  for (int off = 32; off; off >>= 1) s += __shfl_xor(s, off, 64);
  if (tid == 0) out[b] = 1.f / (1.f + __expf(-(s + db[0])));
}

extern "C" void kernel_launch(void* const* d_in, const int* in_sizes, int n_in,
                              void* d_out, int out_size, void* d_ws, size_t ws_size,
                              hipStream_t stream) {
  const float* x         = (const float*)d_in[0];
  const float* enc_w     = (const float*)d_in[1];
  const float* enc_b     = (const float*)d_in[2];
  const float* norm_w    = (const float*)d_in[3];
  const float* in_proj_w = (const float*)d_in[4];
  const float* conv_w    = (const float*)d_in[5];
  const float* conv_b    = (const float*)d_in[6];
  const float* x_proj_w  = (const float*)d_in[7];
  const float* dt_proj_w = (const float*)d_in[8];
  const float* dt_proj_b = (const float*)d_in[9];
  const float* A_log     = (const float*)d_in[10];
  const float* D_param   = (const float*)d_in[11];
  const float* out_proj_w= (const float*)d_in[12];
  const float* dec_w     = (const float*)d_in[13];
  const float* dec_b     = (const float*)d_in[14];
  float* out = (float*)d_out;

  float* ws = (float*)d_ws;
  float* h      = ws;                       // 2M f32
  float* hend   = ws + 2097152;             // 2M f32 (normed16 aliases this pre-scan)
  float* xz     = ws + 4194304;             // 8M f32
  u16*   xbc16  = (u16*)(ws + 12582912);    // 4M u16 (2M f32 slots)
  float* dbc    = ws + 14680064;            // 393216 f32
  float* delta  = ws + 15073280;            // 4M f32
  u16*   w16in  = (u16*)(ws + 19267584);    // 524288 u16
  u16*   w16out = (u16*)(ws + 19529728);    // 262144 u16
  u16*   w16xp  = (u16*)(ws + 19660800);    // 49152 u16
  u16*   normed16 = (u16*)hend;

  const dim3 blk(256);

  cvt_weights_k<<<(S_IN + S_OUT + S_XP + 255) / 256, blk, 0, stream>>>(
      in_proj_w, out_proj_w, x_proj_w, w16in, w16out, w16xp);

  gemm_nt<true, false><<<dim3(DM / 64, MROWS / 64), blk, 0, stream>>>(
      x, enc_w, enc_b, h, MROWS, DM, INDIM, INDIM);

  for (int l = 0; l < 2; l++) {
    const float* Al = A_log + (size_t)l * ED * NST;
    rmsnorm_k<<<MROWS, 256, 0, stream>>>(h, norm_w + (size_t)l * DM, normed16);
    gemm_bf16<false><<<dim3(1024 / 128, MROWS / 128), blk, 0, stream>>>(
        normed16, w16in + (size_t)l * 1024 * DM, xz, MROWS, 1024, DM, DM, 1024);
    conv_silu_k<<<(MROWS * ED + 255) / 256, blk, 0, stream>>>(
        xz, conv_w + (size_t)l * ED * 4, conv_b + (size_t)l * ED, xbc16);
    gemm_bf16<false><<<dim3(1, MROWS / 128), blk, 0, stream>>>(
        xbc16, w16xp + (size_t)l * 48 * ED, dbc, MROWS, 48, ED, ED, 48);
    dt_softplus_k<<<dim3(2, MROWS), blk, 0, stream>>>(
        dbc, dt_proj_w + (size_t)l * ED * DTR, dt_proj_b + (size_t)l * ED, delta);
    scan_pass1<<<dim3(ED / 256, CH, BSZ), blk, 0, stream>>>(
        delta, xbc16, dbc, xz, hend, Al);
    scan_mid<<<(BSZ * ED * NST) / 256, blk, 0, stream>>>(hend, xz, Al);
    scan_pass2<<<dim3(ED / 256, CH, BSZ), blk, 0, stream>>>(
        delta, xbc16, dbc, xz, hend, Al, D_param + (size_t)l * ED);
    gemm_bf16<true><<<dim3(DM / 128, MROWS / 128), blk, 0, stream>>>(
        (const u16*)xz, w16out + (size_t)l * DM * ED, h, MROWS, DM, ED, 2048, DM);
  }

  decode_k<<<4, 64, 0, stream>>>(h, dec_w, dec_b, out);
}